// Round 14
// baseline (2326.302 us; speedup 1.0000x reference)
//
#include <hip/hip_runtime.h>

typedef int   v4i  __attribute__((ext_vector_type(4)));
typedef int   v16i __attribute__((ext_vector_type(16)));
typedef float f4   __attribute__((ext_vector_type(4)));

#define DD 4096
#define BATCH 16384

// async global->LDS, 16B per lane. LDS dest is wave-uniform base + lane*16.
__device__ __forceinline__ void gload16(const void* g, void* l) {
  __builtin_amdgcn_global_load_lds((const __attribute__((address_space(1))) void*)g,
                                   (__attribute__((address_space(3))) void*)l, 16, 0, 0);
}
#define ASM_VMCNT(n) asm volatile("s_waitcnt vmcnt(" #n ")" ::: "memory")
#define ASM_LGKM(n)  asm volatile("s_waitcnt lgkmcnt(" #n ")" ::: "memory")
#define BARF()       asm volatile("s_barrier" ::: "memory")   // barrier + compiler fence
#define SCHED0()     __builtin_amdgcn_sched_barrier(0)

// v2 layouts (swizzle baked into GLOBAL layout; staging = linear copy; read XORs):
//  bin layout  (64B rows): byte(row,k) at row*4096 + (k&~63) + slot*16 + (k&15),
//              slot = seg ^ swz2(row),  swz2(row) = ((row>>1)&3) ^ ((row>>3)&1)
//  digit layout(256B/row/kblk): slot16 = ((d<<2)|seg) ^ (row&15)
__device__ __forceinline__ int swz2(int row) { return ((row >> 1) & 3) ^ ((row >> 3) & 1); }

// ---------- binarize f32 -> +-1 i8, bin-swizzled layout (swz_on=0 for w3) ----------
__global__ void binarize_swz_k(const float* __restrict__ w, unsigned char* __restrict__ o,
                               int swz_on) {
  int T = blockIdx.x * blockDim.x + threadIdx.x;
  int row = T >> 10, rem = T & 1023;
  int kblk = rem >> 4, seg = (rem >> 2) & 3, q = rem & 3;
  f4 v = *(const f4*)(w + (size_t)row * DD + kblk * 64 + seg * 16 + q * 4);
  unsigned int r = 0;
#pragma unroll
  for (int j = 0; j < 4; ++j) {
    unsigned int b = (v[j] >= 0.0f) ? 0x01u : 0xFFu;
    r |= b << (8 * j);
  }
  int slot = swz_on ? (seg ^ swz2(row)) : seg;
  *(unsigned int*)(o + (size_t)row * DD + kblk * 64 + slot * 16 + q * 4) = r;
}

// ---------- row-sum of binarized w0 (order-invariant under swizzle) ----------
__global__ void rowsum_k(const unsigned char* __restrict__ wb, int* __restrict__ R) {
  int lane = threadIdx.x & 63, wid = threadIdx.x >> 6;
  int row = blockIdx.x * 4 + wid;
  const unsigned char* p = wb + (size_t)row * DD;
  int s = 0;
#pragma unroll
  for (int j = 0; j < 4; ++j) {
    v4i a = *(const v4i*)(p + lane * 16 + j * 1024);
#pragma unroll
    for (int w = 0; w < 4; ++w) {
      unsigned int xa = (unsigned int)a[w];
#pragma unroll
      for (int by = 0; by < 4; ++by)
        s += (int)(signed char)((xa >> (8 * by)) & 255u);
    }
  }
#pragma unroll
  for (int off = 32; off > 0; off >>= 1) s += __shfl_down(s, off);
  if (lane == 0) R[row] = s;
}

// ---------- digitize x: f32 -> 4 exact i8 digit planes, digit-swizzled v2 ----------
__global__ void digitize_k(const float* __restrict__ x, unsigned char* __restrict__ Xd) {
  int T = blockIdx.x * blockDim.x + threadIdx.x;
  int row = T >> 10, rem = T & 1023;
  int kblk = rem >> 4, seg = (rem >> 2) & 3, q = rem & 3;
  f4 v = *(const f4*)(x + (size_t)row * DD + kblk * 64 + seg * 16 + q * 4);
  unsigned int Y[4];
#pragma unroll
  for (int j = 0; j < 4; ++j) {
    int X = (int)(v[j] * 134217728.0f);
    Y[j] = (unsigned int)(X + 1073741824);
  }
  size_t base = (size_t)row * 16384 + (size_t)kblk * 256;
  int r15 = row & 15;
#pragma unroll
  for (int d = 0; d < 4; ++d) {
    unsigned int wv = ((Y[0] >> (8 * d)) & 255u)
                    | (((Y[1] >> (8 * d)) & 255u) << 8)
                    | (((Y[2] >> (8 * d)) & 255u) << 16)
                    | (((Y[3] >> (8 * d)) & 255u) << 24);
    wv ^= 0x80808080u;
    int slot = ((d << 2) | seg) ^ r15;
    *(unsigned int*)(Xd + base + slot * 16 + q * 4) = wv;
  }
}

// ---------- layer 0: i8 GEMM over 4 digit planes ----------
// R8 geometry (64x128 tile, 4 waves 2Mx2N, 2 blocks/CU). NEW: triple-buffered,
// 4 counted-lgkm phases per K-tile, ZERO intra-tile drains, ONE barrier/K-tile.
__global__ __launch_bounds__(256, 2) void gemm0p_k(
    const unsigned char* __restrict__ Xd, const unsigned char* __restrict__ wb,
    const int* __restrict__ R, const float* __restrict__ bias,
    signed char* __restrict__ h1) {
  __shared__ __align__(16) unsigned char As[3][64 * 256];    // 16 KB each
  __shared__ __align__(16) unsigned char Bs[3][128 * 64];    // 8 KB each -> 72 KB
  const int tid = threadIdx.x, lane = tid & 63, wid = tid >> 6;
  const int wm = wid >> 1, wn = wid & 1;       // 2x2 waves, wave tile 32x64
  const int bid = blockIdx.x;
  const int xcd = bid & 7, sl = bid >> 3;      // sl in 0..1023
  const int m0 = ((xcd << 5) + (sl >> 5)) << 6;
  const int n0 = (sl & 31) << 7;

  v16i acc[4][2];
#pragma unroll
  for (int d = 0; d < 4; ++d)
#pragma unroll
    for (int f = 0; f < 2; ++f)
#pragma unroll
      for (int e = 0; e < 16; ++e) acc[d][f][e] = 0;

  auto stageA2 = [&](int bf, int kb, int half) {   // 2 A gloads (chunks of 4 rows)
#pragma unroll
    for (int i = 0; i < 2; ++i) {
      int c = wid * 4 + half * 2 + i;
      int lrow = c * 4 + (lane >> 4);
      const unsigned char* g = Xd + (size_t)(m0 + lrow) * 16384 + (size_t)kb * 256 + (lane & 15) * 16;
      gload16(g, &As[bf][c * 1024]);
    }
  };
  auto stageB1 = [&](int bf, int kb, int half) {   // 1 B gload (chunk of 16 rows)
    int c = wid * 2 + half;
    int lrowB = c * 16 + (lane >> 2);
    const unsigned char* gB = wb + (size_t)(n0 + lrowB) * 4096 + kb * 64 + (lane & 3) * 16;
    gload16(gB, &Bs[bf][c * 1024]);
  };

  const int rl = lane & 31, hi = lane >> 5;
  const int arow = wm * 32 + rl;
  const int r15 = arow & 15;
  const int brow0 = wn * 64 + rl;
  const int brow1 = wn * 64 + 32 + rl;
  const int bsw0 = swz2(brow0), bsw1 = swz2(brow1);

  auto readA2 = [&](v4i* dst, int bf, int dh, int ks) {  // d = 2dh, 2dh+1 at ks
    int g = ks * 2 + hi;
#pragma unroll
    for (int j = 0; j < 2; ++j) {
      int d = 2 * dh + j;
      int slot = ((d << 2) | g) ^ r15;
      dst[j] = *(const v4i*)&As[bf][arow * 256 + slot * 16];
    }
  };
  auto readB2 = [&](v4i* dst, int bf, int ks) {
    int g = ks * 2 + hi;
    dst[0] = *(const v4i*)&Bs[bf][brow0 * 64 + ((g ^ bsw0) * 16)];
    dst[1] = *(const v4i*)&Bs[bf][brow1 * 64 + ((g ^ bsw1) * 16)];
  };

  // prologue: stage kb=0 (buf0), kb=1 (buf1); wait kb0 landed
  stageA2(0, 0, 0); stageA2(0, 0, 1); stageB1(0, 0, 0); stageB1(0, 0, 1);
  stageA2(1, 1, 0); stageA2(1, 1, 1); stageB1(1, 1, 0); stageB1(1, 1, 1);
  ASM_VMCNT(6); BARF();

  int p = 0;
  v4i aA[2], aB[2], aC[2], aD[2], bK0[2], bK1[2];
  for (int kb = 0; kb < 64; ++kb) {
    const int s = (p >= 1) ? p - 1 : 2;          // (p+2)%3
    const bool st = (kb < 62);
    // P0: own frags (4) + P1 lookahead (2); stage A half0
    readA2(aA, p, 0, 0); readB2(bK0, p, 0);
    readA2(aB, p, 1, 0);
    if (st) stageA2(s, kb + 2, 0);
    ASM_LGKM(2); SCHED0();
#pragma unroll
    for (int j = 0; j < 2; ++j)
#pragma unroll
      for (int f = 0; f < 2; ++f)
        acc[j][f] = __builtin_amdgcn_mfma_i32_32x32x32_i8(aA[j], bK0[f], acc[j][f], 0, 0, 0);
    // P1: P2 lookahead (4); stage A half1
    readA2(aC, p, 0, 1); readB2(bK1, p, 1);
    if (st) stageA2(s, kb + 2, 1);
    ASM_LGKM(4); SCHED0();
#pragma unroll
    for (int j = 0; j < 2; ++j)
#pragma unroll
      for (int f = 0; f < 2; ++f)
        acc[2 + j][f] = __builtin_amdgcn_mfma_i32_32x32x32_i8(aB[j], bK0[f], acc[2 + j][f], 0, 0, 0);
    // P2: P3 lookahead (2); stage B half0
    readA2(aD, p, 1, 1);
    if (st) stageB1(s, kb + 2, 0);
    ASM_LGKM(2); SCHED0();
#pragma unroll
    for (int j = 0; j < 2; ++j)
#pragma unroll
      for (int f = 0; f < 2; ++f)
        acc[j][f] = __builtin_amdgcn_mfma_i32_32x32x32_i8(aC[j], bK1[f], acc[j][f], 0, 0, 0);
    // P3: stage B half1
    if (st) stageB1(s, kb + 2, 1);
    ASM_LGKM(0); SCHED0();
#pragma unroll
    for (int j = 0; j < 2; ++j)
#pragma unroll
      for (int f = 0; f < 2; ++f)
        acc[2 + j][f] = __builtin_amdgcn_mfma_i32_32x32x32_i8(aD[j], bK1[f], acc[2 + j][f], 0, 0, 0);
    // K-tile end: counted vmcnt proves kb+1's buffer landed; kb+2's still flying
    if (kb < 62)      { ASM_VMCNT(6); BARF(); }
    else if (kb == 62){ ASM_VMCNT(0); BARF(); }
    p = (p < 2) ? p + 1 : 0;
  }

#pragma unroll
  for (int f = 0; f < 2; ++f) {
    int col = n0 + wn * 64 + f * 32 + (lane & 31);
    long long rterm = 1082163328LL * (long long)R[col];
    double bb = (double)bias[col];
#pragma unroll
    for (int r = 0; r < 16; ++r) {
      long long Z = (long long)acc[0][f][r] + 256LL * (long long)acc[1][f][r]
                  + 65536LL * (long long)acc[2][f][r] + 16777216LL * (long long)acc[3][f][r]
                  + rterm;
      double z = (double)Z * 7.450580596923828125e-9 + bb;
      int row = m0 + wm * 32 + (r & 3) + 8 * (r >> 2) + 4 * (lane >> 5);
      int col2 = col ^ (swz2(row) << 4);       // bin-swizzled v2 output
      h1[(size_t)row * DD + col2] = (z >= 0.0) ? (signed char)1 : (signed char)(-1);
    }
  }
}

// ---------- layer 0 fallback (ws too small): in-kernel digitization ----------
__global__ __launch_bounds__(512, 2) void gemm0f_k(
    const float* __restrict__ x, const unsigned char* __restrict__ wb,
    const int* __restrict__ R, const float* __restrict__ bias,
    signed char* __restrict__ h1) {
  __shared__ signed char As[2][4][128 * 80];
  __shared__ signed char Bs[2][128 * 80];
  const int tid = threadIdx.x;
  const int lane = tid & 63, wid = tid >> 6;
  const int wm = wid >> 1, wn = wid & 1;
  const int n0 = blockIdx.x * 128, m0 = blockIdx.y * 128;

  v16i acc[4][2];
#pragma unroll
  for (int d = 0; d < 4; ++d)
#pragma unroll
    for (int f = 0; f < 2; ++f)
#pragma unroll
      for (int e = 0; e < 16; ++e) acc[d][f][e] = 0;

  const int arow_l = tid >> 4, aseg = tid & 15;
  const int brow = tid >> 2,  bseg = (tid & 3) * 16;
  f4 va[4]; v4i vb;

  auto loadTile = [&](int kpos) {
#pragma unroll
    for (int p = 0; p < 4; ++p)
      va[p] = *(const f4*)(x + (size_t)(m0 + p * 32 + arow_l) * DD + kpos + aseg * 4);
    vb = *(const v4i*)(wb + (size_t)(n0 + brow) * DD + kpos + bseg);
  };
  auto writeTile = [&](int bf) {
#pragma unroll
    for (int p = 0; p < 4; ++p) {
      int row = p * 32 + arow_l;
      unsigned int Y[4];
#pragma unroll
      for (int j = 0; j < 4; ++j) {
        int X = (int)(va[p][j] * 134217728.0f);
        Y[j] = (unsigned int)(X + 1073741824);
      }
#pragma unroll
      for (int k = 0; k < 4; ++k) {
        unsigned int wv = ((Y[0] >> (8 * k)) & 255u) | (((Y[1] >> (8 * k)) & 255u) << 8)
                        | (((Y[2] >> (8 * k)) & 255u) << 16) | (((Y[3] >> (8 * k)) & 255u) << 24);
        wv ^= 0x80808080u;
        *(unsigned int*)&As[bf][k][row * 80 + aseg * 4] = wv;
      }
    }
    *(v4i*)&Bs[bf][brow * 80 + bseg] = vb;
  };

  loadTile(0); writeTile(0);
  __syncthreads();
  for (int t = 0; t < 64; ++t) {
    int cur = t & 1;
    if (t < 63) loadTile((t + 1) * 64);
#pragma unroll
    for (int kt = 0; kt < 2; ++kt) {
      int g = kt * 2 + (lane >> 5);
      int ar = (wm * 32 + (lane & 31)) * 80 + g * 16;
      v4i a[4], b[2];
#pragma unroll
      for (int d = 0; d < 4; ++d) a[d] = *(const v4i*)&As[cur][d][ar];
#pragma unroll
      for (int f = 0; f < 2; ++f) {
        int br = wn * 64 + f * 32 + (lane & 31);
        int slotb = g ^ swz2(br);
        b[f] = *(const v4i*)&Bs[cur][br * 80 + slotb * 16];
      }
#pragma unroll
      for (int d = 0; d < 4; ++d)
#pragma unroll
        for (int f = 0; f < 2; ++f)
          acc[d][f] = __builtin_amdgcn_mfma_i32_32x32x32_i8(a[d], b[f], acc[d][f], 0, 0, 0);
    }
    if (t < 63) writeTile(cur ^ 1);
    __syncthreads();
  }

#pragma unroll
  for (int f = 0; f < 2; ++f) {
    int col = n0 + wn * 64 + f * 32 + (lane & 31);
    long long rterm = 1082163328LL * (long long)R[col];
    double bb = (double)bias[col];
#pragma unroll
    for (int r = 0; r < 16; ++r) {
      long long Z = (long long)acc[0][f][r] + 256LL * (long long)acc[1][f][r]
                  + 65536LL * (long long)acc[2][f][r] + 16777216LL * (long long)acc[3][f][r]
                  + rterm;
      double z = (double)Z * 7.450580596923828125e-9 + bb;
      int row = m0 + wm * 32 + (r & 3) + 8 * (r >> 2) + 4 * (lane >> 5);
      int col2 = col ^ (swz2(row) << 4);
      h1[(size_t)row * DD + col2] = (z >= 0.0) ? (signed char)1 : (signed char)(-1);
    }
  }
}

// ---------- binary x binary layers ----------
// R8 geometry (128x128 tile, 4 waves, 3 blocks/CU). NEW: triple-buffered,
// 2 counted-lgkm phases per K-tile, zero drains, one barrier/K-tile.
__global__ __launch_bounds__(256, 3) void gemm_bin_k(
    const unsigned char* __restrict__ A, const unsigned char* __restrict__ Bw,
    const float* __restrict__ bias, signed char* __restrict__ out) {
  __shared__ __align__(16) unsigned char As[3][128 * 64];    // 8 KB each
  __shared__ __align__(16) unsigned char Bs[3][128 * 64];    // -> 48 KB total
  const int tid = threadIdx.x, lane = tid & 63, wid = tid >> 6;
  const int wm = wid >> 1, wn = wid & 1;       // 2x2 waves, wave tile 64x64
  const int bid = blockIdx.x;
  const int xcd = bid & 7, sl = bid >> 3;      // sl in 0..511
  const int m0 = ((xcd << 4) + (sl >> 5)) << 7;
  const int n0 = (sl & 31) << 7;

  v16i acc[2][2];
#pragma unroll
  for (int mi = 0; mi < 2; ++mi)
#pragma unroll
    for (int f = 0; f < 2; ++f)
#pragma unroll
      for (int e = 0; e < 16; ++e) acc[mi][f][e] = 0;

  auto stageA = [&](int bf, int kb) {          // 2 A gloads
#pragma unroll
    for (int j = 0; j < 2; ++j) {
      int c = wid * 2 + j;
      int lrow = c * 16 + (lane >> 2);
      const unsigned char* gA = A + (size_t)(m0 + lrow) * 4096 + kb * 64 + (lane & 3) * 16;
      gload16(gA, &As[bf][c * 1024]);
    }
  };
  auto stageB = [&](int bf, int kb) {          // 2 B gloads
#pragma unroll
    for (int j = 0; j < 2; ++j) {
      int c = wid * 2 + j;
      int lrow = c * 16 + (lane >> 2);
      const unsigned char* gB = Bw + (size_t)(n0 + lrow) * 4096 + kb * 64 + (lane & 3) * 16;
      gload16(gB, &Bs[bf][c * 1024]);
    }
  };

  const int rl = lane & 31, hi = lane >> 5;
  const int arow0 = wm * 64 + rl,      arow1 = wm * 64 + 32 + rl;
  const int brow0 = wn * 64 + rl,      brow1 = wn * 64 + 32 + rl;
  const int asw0 = swz2(arow0), asw1 = swz2(arow1);
  const int bsw0 = swz2(brow0), bsw1 = swz2(brow1);

  auto readKS = [&](v4i* fa, v4i* fb, int bf, int ks) {   // 4 reads
    int g = ks * 2 + hi;
    fa[0] = *(const v4i*)&As[bf][arow0 * 64 + ((g ^ asw0) * 16)];
    fa[1] = *(const v4i*)&As[bf][arow1 * 64 + ((g ^ asw1) * 16)];
    fb[0] = *(const v4i*)&Bs[bf][brow0 * 64 + ((g ^ bsw0) * 16)];
    fb[1] = *(const v4i*)&Bs[bf][brow1 * 64 + ((g ^ bsw1) * 16)];
  };

  stageA(0, 0); stageB(0, 0);
  stageA(1, 1); stageB(1, 1);
  ASM_VMCNT(4); BARF();

  int p = 0;
  v4i fa0[2], fb0[2], fa1[2], fb1[2];
  for (int kb = 0; kb < 64; ++kb) {
    const int s = (p >= 1) ? p - 1 : 2;
    const bool st = (kb < 62);
    // P0: own frags (4) + ks1 lookahead (4); stage A
    readKS(fa0, fb0, p, 0);
    readKS(fa1, fb1, p, 1);
    if (st) stageA(s, kb + 2);
    ASM_LGKM(4); SCHED0();
#pragma unroll
    for (int mi = 0; mi < 2; ++mi)
#pragma unroll
      for (int f = 0; f < 2; ++f)
        acc[mi][f] = __builtin_amdgcn_mfma_i32_32x32x32_i8(fa0[mi], fb0[f], acc[mi][f], 0, 0, 0);
    // P1: stage B
    if (st) stageB(s, kb + 2);
    ASM_LGKM(0); SCHED0();
#pragma unroll
    for (int mi = 0; mi < 2; ++mi)
#pragma unroll
      for (int f = 0; f < 2; ++f)
        acc[mi][f] = __builtin_amdgcn_mfma_i32_32x32x32_i8(fa1[mi], fb1[f], acc[mi][f], 0, 0, 0);
    if (kb < 62)      { ASM_VMCNT(4); BARF(); }
    else if (kb == 62){ ASM_VMCNT(0); BARF(); }
    p = (p < 2) ? p + 1 : 0;
  }

#pragma unroll
  for (int mi = 0; mi < 2; ++mi)
#pragma unroll
    for (int f = 0; f < 2; ++f) {
      int col = n0 + wn * 64 + f * 32 + (lane & 31);
      float bb = bias[col];
#pragma unroll
      for (int r = 0; r < 16; ++r) {
        float z = (float)acc[mi][f][r] + bb;
        int row = m0 + wm * 64 + mi * 32 + (r & 3) + 8 * (r >> 2) + 4 * (lane >> 5);
        int col2 = col ^ (swz2(row) << 4);
        out[(size_t)row * DD + col2] = (z >= 0.0f) ? (signed char)1 : (signed char)(-1);
      }
    }
}

// ---------- final layer: h (bin-swizzled v2) x w3b (plain) ----------
__global__ void final_k(const unsigned char* __restrict__ h, const unsigned char* __restrict__ w3b,
                        const float* __restrict__ b3, float* __restrict__ out) {
  int lane = threadIdx.x & 63, wid = threadIdx.x >> 6;
  int row = blockIdx.x * 4 + wid;
  int swz = swz2(row) << 4;
  const unsigned char* p = h + (size_t)row * DD;
  int s = 0;
#pragma unroll
  for (int j = 0; j < 4; ++j) {
    int e = lane * 16 + j * 1024;
    v4i a = *(const v4i*)(p + (e ^ swz));
    v4i b = *(const v4i*)(w3b + e);
#pragma unroll
    for (int w = 0; w < 4; ++w) {
      unsigned int xa = (unsigned int)a[w], xb = (unsigned int)b[w];
#pragma unroll
      for (int by = 0; by < 4; ++by)
        s += (int)(signed char)((xa >> (8 * by)) & 255u)
           * (int)(signed char)((xb >> (8 * by)) & 255u);
    }
  }
#pragma unroll
  for (int off = 32; off > 0; off >>= 1) s += __shfl_down(s, off);
  if (lane == 0) {
    float z = (float)s + b3[0];
    out[row] = (z >= 0.0f) ? 1.0f : -1.0f;
  }
}

extern "C" void kernel_launch(void* const* d_in, const int* in_sizes, int n_in,
                              void* d_out, int out_size, void* d_ws, size_t ws_size,
                              hipStream_t stream) {
  (void)in_sizes; (void)n_in; (void)out_size;
  const float* x  = (const float*)d_in[0];
  const float* w0 = (const float*)d_in[1];
  const float* b0 = (const float*)d_in[2];
  const float* w1 = (const float*)d_in[3];
  const float* b1 = (const float*)d_in[4];
  const float* w2 = (const float*)d_in[5];
  const float* b2 = (const float*)d_in[6];
  const float* w3 = (const float*)d_in[7];
  const float* b3 = (const float*)d_in[8];

  char* ws = (char*)d_ws;
  unsigned char* w0b = (unsigned char*)(ws + 0);
  unsigned char* w1b = (unsigned char*)(ws + (16ull << 20));
  unsigned char* w2b = (unsigned char*)(ws + (32ull << 20));
  unsigned char* w3b = (unsigned char*)(ws + (48ull << 20));
  int*           R   = (int*)(ws + (48ull << 20) + 65536);
  unsigned char* h1  = (unsigned char*)(ws + (64ull << 20));    // 64 MiB
  unsigned char* h2  = (unsigned char*)(ws + (128ull << 20));   // 64 MiB (aliases Xd head)
  unsigned char* Xd  = (unsigned char*)(ws + (128ull << 20));   // 256 MiB, dead before h2 written
  float* out = (float*)d_out;

  binarize_swz_k<<<16384, 256, 0, stream>>>(w0, w0b, 1);
  binarize_swz_k<<<16384, 256, 0, stream>>>(w1, w1b, 1);
  binarize_swz_k<<<16384, 256, 0, stream>>>(w2, w2b, 1);
  binarize_swz_k<<<4,     256, 0, stream>>>(w3, w3b, 0);
  rowsum_k<<<1024, 256, 0, stream>>>(w0b, R);

  if (ws_size >= (384ull << 20)) {
    digitize_k<<<65536, 256, 0, stream>>>(x, Xd);
    gemm0p_k<<<8192, 256, 0, stream>>>(Xd, w0b, R, b0, (signed char*)h1);
  } else {
    gemm0f_k<<<dim3(32, 128), 512, 0, stream>>>(x, w0b, R, b0, (signed char*)h1);
  }
  gemm_bin_k<<<4096, 256, 0, stream>>>(h1, w1b, b1, (signed char*)h2);
  gemm_bin_k<<<4096, 256, 0, stream>>>(h2, w2b, b2, (signed char*)h1);
  final_k<<<4096, 256, 0, stream>>>(h1, w3b, b3, out);
}

// Round 15
// 1770.247 us; speedup vs baseline: 1.3141x; 1.3141x over previous
//
#include <hip/hip_runtime.h>

typedef int   v4i  __attribute__((ext_vector_type(4)));
typedef int   v16i __attribute__((ext_vector_type(16)));
typedef float f4   __attribute__((ext_vector_type(4)));

#define DD 4096
#define BATCH 16384
#define FIXCAP (1u << 22)          // 4M worklist entries (16 MB)

// async global->LDS, 16B per lane. LDS dest is wave-uniform base + lane*16.
__device__ __forceinline__ void gload16(const void* g, void* l) {
  __builtin_amdgcn_global_load_lds((const __attribute__((address_space(1))) void*)g,
                                   (__attribute__((address_space(3))) void*)l, 16, 0, 0);
}
#define ASM_VMCNT(n) asm volatile("s_waitcnt vmcnt(" #n ")" ::: "memory")
#define ASM_LGKM0()  asm volatile("s_waitcnt lgkmcnt(0)" ::: "memory")
#define BARF()       asm volatile("s_barrier" ::: "memory")   // barrier + compiler fence

// v2 layouts (swizzle baked into GLOBAL layout; staging = linear copy; read XORs):
//  bin layout  (64B rows): byte(row,k) at row*4096 + (k&~63) + slot*16 + (k&15),
//              slot = seg ^ swz2(row),  swz2(row) = ((row>>1)&3) ^ ((row>>3)&1)
//  digit PLANES (3x, scale 2^19): plane d is a bin-layout byte array [16384][4096].
__device__ __forceinline__ int swz2(int row) { return ((row >> 1) & 3) ^ ((row >> 3) & 1); }

// ---------- binarize f32 -> +-1 i8, bin-swizzled layout (swz_on=0 for w3) ----------
__global__ void binarize_swz_k(const float* __restrict__ w, unsigned char* __restrict__ o,
                               int swz_on) {
  int T = blockIdx.x * blockDim.x + threadIdx.x;
  int row = T >> 10, rem = T & 1023;
  int kblk = rem >> 4, seg = (rem >> 2) & 3, q = rem & 3;
  f4 v = *(const f4*)(w + (size_t)row * DD + kblk * 64 + seg * 16 + q * 4);
  unsigned int r = 0;
#pragma unroll
  for (int j = 0; j < 4; ++j) {
    unsigned int b = (v[j] >= 0.0f) ? 0x01u : 0xFFu;
    r |= b << (8 * j);
  }
  int slot = swz_on ? (seg ^ swz2(row)) : seg;
  *(unsigned int*)(o + (size_t)row * DD + kblk * 64 + slot * 16 + q * 4) = r;
}

// ---------- row-sum of binarized w0 (order-invariant under swizzle) ----------
__global__ void rowsum_k(const unsigned char* __restrict__ wb, int* __restrict__ R) {
  int lane = threadIdx.x & 63, wid = threadIdx.x >> 6;
  int row = blockIdx.x * 4 + wid;
  const unsigned char* p = wb + (size_t)row * DD;
  int s = 0;
#pragma unroll
  for (int j = 0; j < 4; ++j) {
    v4i a = *(const v4i*)(p + lane * 16 + j * 1024);
#pragma unroll
    for (int w = 0; w < 4; ++w) {
      unsigned int xa = (unsigned int)a[w];
#pragma unroll
      for (int by = 0; by < 4; ++by)
        s += (int)(signed char)((xa >> (8 * by)) & 255u);
    }
  }
#pragma unroll
  for (int off = 32; off > 0; off >>= 1) s += __shfl_down(s, off);
  if (lane == 0) R[row] = s;
}

// ---------- digitize x: f32 -> 3 exact i8 digit planes (scale 2^19), bin-swizzled ----------
// X=trunc(x*2^19) (exact: pow2 scale); Y=X+2^23 in [0,2^24); byte_d(Y)^0x80 = digit d.
__global__ void digitize3_k(const float* __restrict__ x, unsigned char* __restrict__ Xp) {
  int T = blockIdx.x * blockDim.x + threadIdx.x;
  int row = T >> 10, rem = T & 1023;
  int kblk = rem >> 4, seg = (rem >> 2) & 3, q = rem & 3;
  f4 v = *(const f4*)(x + (size_t)row * DD + kblk * 64 + seg * 16 + q * 4);
  unsigned int Y[4];
#pragma unroll
  for (int j = 0; j < 4; ++j) {
    int X = (int)(v[j] * 524288.0f);
    Y[j] = (unsigned int)(X + 8388608);
  }
  int slot = seg ^ swz2(row);
  size_t base = (size_t)row * DD + kblk * 64 + slot * 16 + q * 4;
#pragma unroll
  for (int d = 0; d < 3; ++d) {
    unsigned int wv = ((Y[0] >> (8 * d)) & 255u)
                    | (((Y[1] >> (8 * d)) & 255u) << 8)
                    | (((Y[2] >> (8 * d)) & 255u) << 16)
                    | (((Y[3] >> (8 * d)) & 255u) << 24);
    wv ^= 0x80808080u;
    *(unsigned int*)(Xp + (size_t)d * (64u << 20) + base) = wv;
  }
}

__global__ void zeroc_k(unsigned int* c) { if (threadIdx.x == 0) *c = 0; }

// ---------- layer 0: i8 GEMM over 3 digit planes (R8 schedule) + boundary flagging ----------
// 256-thread blocks (4 waves, 2Mx2N), block tile 64x128, 2 blocks/CU.
// |z19 - z27| <= 4096*(2^-19 + 2^-27) = 0.00784 < 0.0079 = flag threshold.
__global__ __launch_bounds__(256, 2) void gemm0p3_k(
    const unsigned char* __restrict__ Xp, const unsigned char* __restrict__ wb,
    const int* __restrict__ R, const float* __restrict__ bias,
    signed char* __restrict__ h1,
    unsigned int* __restrict__ wl, unsigned int* __restrict__ cnt) {
  __shared__ __align__(16) unsigned char Asp[2][3][64 * 64];  // 3 planes x 4 KB per buf
  __shared__ __align__(16) unsigned char Bs[2][128 * 64];     // 8 KB per buf
  const int tid = threadIdx.x, lane = tid & 63, wid = tid >> 6;
  const int wm = wid >> 1, wn = wid & 1;       // 2x2 waves, wave tile 32x64
  const int bid = blockIdx.x;
  const int xcd = bid & 7, sl = bid >> 3;      // sl in 0..1023
  const int m0 = ((xcd << 5) + (sl >> 5)) << 6;
  const int n0 = (sl & 31) << 7;

  v16i acc[3][2];
#pragma unroll
  for (int d = 0; d < 3; ++d)
#pragma unroll
    for (int f = 0; f < 2; ++f)
#pragma unroll
      for (int e = 0; e < 16; ++e) acc[d][f][e] = 0;

  auto stage = [&](int bf, int kb) {           // 5 gloads/wave: 3 A-plane chunks + 2 B
#pragma unroll
    for (int i = 0; i < 3; ++i) {
      int c = wid * 3 + i;                     // 0..11: plane d = c>>2, sub-tile = c&3
      int d = c >> 2, sub = c & 3;
      int lrow = sub * 16 + (lane >> 2);
      const unsigned char* g = Xp + (size_t)d * (64u << 20)
                             + (size_t)(m0 + lrow) * 4096 + kb * 64 + (lane & 3) * 16;
      gload16(g, &Asp[bf][d][sub * 1024]);
    }
#pragma unroll
    for (int j = 0; j < 2; ++j) {              // B: 8 chunks of 16 rows (1 KB)
      int c = wid * 2 + j;
      int lrowB = c * 16 + (lane >> 2);
      const unsigned char* gB = wb + (size_t)(n0 + lrowB) * 4096 + kb * 64 + (lane & 3) * 16;
      gload16(gB, &Bs[bf][c * 1024]);
    }
  };

  const int rl = lane & 31, hi = lane >> 5;
  const int arow = wm * 32 + rl;
  const int asw = swz2(arow);
  const int brow0 = wn * 64 + rl, brow1 = wn * 64 + 32 + rl;
  const int bsw0 = swz2(brow0), bsw1 = swz2(brow1);

  stage(0, 0);
  stage(1, 1);
  ASM_VMCNT(5); BARF();                        // buf0 ready everywhere
  int cur = 0;
  for (int t = 0; t < 64; ++t) {
    v4i af[2][3], bg[2][2];
#pragma unroll
    for (int kt = 0; kt < 2; ++kt) {
      int g = kt * 2 + hi;
#pragma unroll
      for (int d = 0; d < 3; ++d)
        af[kt][d] = *(const v4i*)&Asp[cur][d][arow * 64 + ((g ^ asw) * 16)];
      bg[kt][0] = *(const v4i*)&Bs[cur][brow0 * 64 + ((g ^ bsw0) * 16)];
      bg[kt][1] = *(const v4i*)&Bs[cur][brow1 * 64 + ((g ^ bsw1) * 16)];
    }
    ASM_LGKM0(); BARF();                       // all waves done reading buf[cur]
    if (t < 62) stage(cur, t + 2);             // refill issue rides under MFMA
    __builtin_amdgcn_s_setprio(1);
#pragma unroll
    for (int kt = 0; kt < 2; ++kt)
#pragma unroll
      for (int d = 0; d < 3; ++d)
#pragma unroll
        for (int f = 0; f < 2; ++f)
          acc[d][f] = __builtin_amdgcn_mfma_i32_32x32x32_i8(af[kt][d], bg[kt][f], acc[d][f], 0, 0, 0);
    __builtin_amdgcn_s_setprio(0);
    if (t < 62) { ASM_VMCNT(5); BARF(); }      // next buf's loads (issued t-1) done
    else if (t == 62) { ASM_VMCNT(0); BARF(); }
    cur ^= 1;
  }

  // z19 = (SA0 + 256*SA1 + 65536*SA2 + 32896*R_col) * 2^-19 ; flag |z19+b| <= 0.0079
#pragma unroll
  for (int f = 0; f < 2; ++f) {
    int col = n0 + wn * 64 + f * 32 + (lane & 31);
    long long rterm = 32896LL * (long long)R[col];
    double bb = (double)bias[col];
#pragma unroll
    for (int r = 0; r < 16; ++r) {
      long long Z = (long long)acc[0][f][r] + 256LL * (long long)acc[1][f][r]
                  + 65536LL * (long long)acc[2][f][r] + rterm;
      double z = (double)Z * 1.9073486328125e-6 + bb;   // * 2^-19
      int row = m0 + wm * 32 + (r & 3) + 8 * (r >> 2) + 4 * (lane >> 5);
      int col2 = col ^ (swz2(row) << 4);
      h1[(size_t)row * DD + col2] = (z >= 0.0) ? (signed char)1 : (signed char)(-1);
      if (fabs(z) <= 0.0079) {
        unsigned int idx = atomicAdd(cnt, 1u);
        if (idx < FIXCAP) wl[idx] = ((unsigned int)row << 12) | (unsigned int)col;
      }
    }
  }
}

// ---------- fixup: exact 2^27 fixed-point recompute for flagged outputs ----------
__global__ void fixup_k(const float* __restrict__ x, const unsigned char* __restrict__ wb,
                        const float* __restrict__ bias, const unsigned int* __restrict__ wl,
                        const unsigned int* __restrict__ cnt, signed char* __restrict__ h1) {
  unsigned int n = *cnt; if (n > FIXCAP) n = FIXCAP;
  int lane = threadIdx.x & 63;
  int gw = (blockIdx.x * blockDim.x + threadIdx.x) >> 6;
  int nw = (gridDim.x * blockDim.x) >> 6;
  for (unsigned int e = gw; e < n; e += nw) {
    unsigned int ent = wl[e];
    int row = ent >> 12, col = ent & 4095;
    const float* xr = x + (size_t)row * DD;
    const unsigned char* wr = wb + (size_t)col * DD;
    int sw = swz2(col);
    long long s = 0;
#pragma unroll 4
    for (int j = 0; j < 64; ++j) {
      int k = j * 64 + lane;
      int kk = (k & ~63) + ((((k >> 4) & 3) ^ sw) * 16) + (k & 15);
      signed char w = (signed char)wr[kk];
      long long X = (long long)(int)(xr[k] * 134217728.0f);
      s += (w > 0) ? X : -X;
    }
#pragma unroll
    for (int off = 32; off > 0; off >>= 1) s += __shfl_down(s, off);
    if (lane == 0) {
      double z = (double)s * 7.450580596923828125e-9 + (double)bias[col];  // * 2^-27
      int col2 = col ^ (swz2(row) << 4);
      h1[(size_t)row * DD + col2] = (z >= 0.0) ? (signed char)1 : (signed char)(-1);
    }
  }
}

// ---------- layer 0 fallback (ws too small): in-kernel digitization, 4-plane exact ----------
__global__ __launch_bounds__(512, 2) void gemm0f_k(
    const float* __restrict__ x, const unsigned char* __restrict__ wb,
    const int* __restrict__ R, const float* __restrict__ bias,
    signed char* __restrict__ h1) {
  __shared__ signed char As[2][4][128 * 80];
  __shared__ signed char Bs[2][128 * 80];
  const int tid = threadIdx.x;
  const int lane = tid & 63, wid = tid >> 6;
  const int wm = wid >> 1, wn = wid & 1;
  const int n0 = blockIdx.x * 128, m0 = blockIdx.y * 128;

  v16i acc[4][2];
#pragma unroll
  for (int d = 0; d < 4; ++d)
#pragma unroll
    for (int f = 0; f < 2; ++f)
#pragma unroll
      for (int e = 0; e < 16; ++e) acc[d][f][e] = 0;

  const int arow_l = tid >> 4, aseg = tid & 15;
  const int brow = tid >> 2,  bseg = (tid & 3) * 16;
  f4 va[4]; v4i vb;

  auto loadTile = [&](int kpos) {
#pragma unroll
    for (int p = 0; p < 4; ++p)
      va[p] = *(const f4*)(x + (size_t)(m0 + p * 32 + arow_l) * DD + kpos + aseg * 4);
    vb = *(const v4i*)(wb + (size_t)(n0 + brow) * DD + kpos + bseg);
  };
  auto writeTile = [&](int bf) {
#pragma unroll
    for (int p = 0; p < 4; ++p) {
      int row = p * 32 + arow_l;
      unsigned int Y[4];
#pragma unroll
      for (int j = 0; j < 4; ++j) {
        int X = (int)(va[p][j] * 134217728.0f);
        Y[j] = (unsigned int)(X + 1073741824);
      }
#pragma unroll
      for (int k = 0; k < 4; ++k) {
        unsigned int wv = ((Y[0] >> (8 * k)) & 255u) | (((Y[1] >> (8 * k)) & 255u) << 8)
                        | (((Y[2] >> (8 * k)) & 255u) << 16) | (((Y[3] >> (8 * k)) & 255u) << 24);
        wv ^= 0x80808080u;
        *(unsigned int*)&As[bf][k][row * 80 + aseg * 4] = wv;
      }
    }
    *(v4i*)&Bs[bf][brow * 80 + bseg] = vb;
  };

  loadTile(0); writeTile(0);
  __syncthreads();
  for (int t = 0; t < 64; ++t) {
    int cur = t & 1;
    if (t < 63) loadTile((t + 1) * 64);
#pragma unroll
    for (int kt = 0; kt < 2; ++kt) {
      int g = kt * 2 + (lane >> 5);
      int ar = (wm * 32 + (lane & 31)) * 80 + g * 16;
      v4i a[4], b[2];
#pragma unroll
      for (int d = 0; d < 4; ++d) a[d] = *(const v4i*)&As[cur][d][ar];
#pragma unroll
      for (int f = 0; f < 2; ++f) {
        int br = wn * 64 + f * 32 + (lane & 31);
        int slotb = g ^ swz2(br);
        b[f] = *(const v4i*)&Bs[cur][br * 80 + slotb * 16];
      }
#pragma unroll
      for (int d = 0; d < 4; ++d)
#pragma unroll
        for (int f = 0; f < 2; ++f)
          acc[d][f] = __builtin_amdgcn_mfma_i32_32x32x32_i8(a[d], b[f], acc[d][f], 0, 0, 0);
    }
    if (t < 63) writeTile(cur ^ 1);
    __syncthreads();
  }

#pragma unroll
  for (int f = 0; f < 2; ++f) {
    int col = n0 + wn * 64 + f * 32 + (lane & 31);
    long long rterm = 1082163328LL * (long long)R[col];
    double bb = (double)bias[col];
#pragma unroll
    for (int r = 0; r < 16; ++r) {
      long long Z = (long long)acc[0][f][r] + 256LL * (long long)acc[1][f][r]
                  + 65536LL * (long long)acc[2][f][r] + 16777216LL * (long long)acc[3][f][r]
                  + rterm;
      double z = (double)Z * 7.450580596923828125e-9 + bb;
      int row = m0 + wm * 32 + (r & 3) + 8 * (r >> 2) + 4 * (lane >> 5);
      int col2 = col ^ (swz2(row) << 4);
      h1[(size_t)row * DD + col2] = (z >= 0.0) ? (signed char)1 : (signed char)(-1);
    }
  }
}

// ---------- binary x binary layers (R8 verbatim) ----------
__global__ __launch_bounds__(256, 3) void gemm_bin_k(
    const unsigned char* __restrict__ A, const unsigned char* __restrict__ Bw,
    const float* __restrict__ bias, signed char* __restrict__ out) {
  __shared__ __align__(16) unsigned char As[2][128 * 64];
  __shared__ __align__(16) unsigned char Bs[2][128 * 64];
  const int tid = threadIdx.x, lane = tid & 63, wid = tid >> 6;
  const int wm = wid >> 1, wn = wid & 1;
  const int bid = blockIdx.x;
  const int xcd = bid & 7, sl = bid >> 3;
  const int m0 = ((xcd << 4) + (sl >> 5)) << 7;
  const int n0 = (sl & 31) << 7;

  v16i acc[2][2];
#pragma unroll
  for (int mi = 0; mi < 2; ++mi)
#pragma unroll
    for (int f = 0; f < 2; ++f)
#pragma unroll
      for (int e = 0; e < 16; ++e) acc[mi][f][e] = 0;

  auto stage = [&](int bf, int kb) {
#pragma unroll
    for (int j = 0; j < 2; ++j) {
      int c = wid * 2 + j;
      int lrow = c * 16 + (lane >> 2);
      const unsigned char* gA = A  + (size_t)(m0 + lrow) * 4096 + kb * 64 + (lane & 3) * 16;
      const unsigned char* gB = Bw + (size_t)(n0 + lrow) * 4096 + kb * 64 + (lane & 3) * 16;
      gload16(gA, &As[bf][c * 1024]);
      gload16(gB, &Bs[bf][c * 1024]);
    }
  };

  const int rl = lane & 31, hi = lane >> 5;

  stage(0, 0);
  stage(1, 1);
  ASM_VMCNT(4); BARF();
  int cur = 0;
  for (int t = 0; t < 64; ++t) {
    v4i af[2][2], bg[2][2];
#pragma unroll
    for (int kt = 0; kt < 2; ++kt) {
      int g = kt * 2 + hi;
#pragma unroll
      for (int mi = 0; mi < 2; ++mi) {
        int arow = wm * 64 + mi * 32 + rl;
        int slot = g ^ swz2(arow);
        af[kt][mi] = *(const v4i*)&As[cur][arow * 64 + slot * 16];
      }
#pragma unroll
      for (int f = 0; f < 2; ++f) {
        int brow = wn * 64 + f * 32 + rl;
        int slot = g ^ swz2(brow);
        bg[kt][f] = *(const v4i*)&Bs[cur][brow * 64 + slot * 16];
      }
    }
    ASM_LGKM0(); BARF();
    if (t < 62) stage(cur, t + 2);
    __builtin_amdgcn_s_setprio(1);
#pragma unroll
    for (int kt = 0; kt < 2; ++kt)
#pragma unroll
      for (int mi = 0; mi < 2; ++mi)
#pragma unroll
        for (int f = 0; f < 2; ++f)
          acc[mi][f] = __builtin_amdgcn_mfma_i32_32x32x32_i8(af[kt][mi], bg[kt][f], acc[mi][f], 0, 0, 0);
    __builtin_amdgcn_s_setprio(0);
    if (t < 62) { ASM_VMCNT(4); BARF(); }
    else if (t == 62) { ASM_VMCNT(0); BARF(); }
    cur ^= 1;
  }

#pragma unroll
  for (int mi = 0; mi < 2; ++mi)
#pragma unroll
    for (int f = 0; f < 2; ++f) {
      int col = n0 + wn * 64 + f * 32 + (lane & 31);
      float bb = bias[col];
#pragma unroll
      for (int r = 0; r < 16; ++r) {
        float z = (float)acc[mi][f][r] + bb;
        int row = m0 + wm * 64 + mi * 32 + (r & 3) + 8 * (r >> 2) + 4 * (lane >> 5);
        int col2 = col ^ (swz2(row) << 4);
        out[(size_t)row * DD + col2] = (z >= 0.0f) ? (signed char)1 : (signed char)(-1);
      }
    }
}

// ---------- final layer: h (bin-swizzled v2) x w3b (plain) ----------
__global__ void final_k(const unsigned char* __restrict__ h, const unsigned char* __restrict__ w3b,
                        const float* __restrict__ b3, float* __restrict__ out) {
  int lane = threadIdx.x & 63, wid = threadIdx.x >> 6;
  int row = blockIdx.x * 4 + wid;
  int swz = swz2(row) << 4;
  const unsigned char* p = h + (size_t)row * DD;
  int s = 0;
#pragma unroll
  for (int j = 0; j < 4; ++j) {
    int e = lane * 16 + j * 1024;
    v4i a = *(const v4i*)(p + (e ^ swz));
    v4i b = *(const v4i*)(w3b + e);
#pragma unroll
    for (int w = 0; w < 4; ++w) {
      unsigned int xa = (unsigned int)a[w], xb = (unsigned int)b[w];
#pragma unroll
      for (int by = 0; by < 4; ++by)
        s += (int)(signed char)((xa >> (8 * by)) & 255u)
           * (int)(signed char)((xb >> (8 * by)) & 255u);
    }
  }
#pragma unroll
  for (int off = 32; off > 0; off >>= 1) s += __shfl_down(s, off);
  if (lane == 0) {
    float z = (float)s + b3[0];
    out[row] = (z >= 0.0f) ? 1.0f : -1.0f;
  }
}

extern "C" void kernel_launch(void* const* d_in, const int* in_sizes, int n_in,
                              void* d_out, int out_size, void* d_ws, size_t ws_size,
                              hipStream_t stream) {
  (void)in_sizes; (void)n_in; (void)out_size;
  const float* x  = (const float*)d_in[0];
  const float* w0 = (const float*)d_in[1];
  const float* b0 = (const float*)d_in[2];
  const float* w1 = (const float*)d_in[3];
  const float* b1 = (const float*)d_in[4];
  const float* w2 = (const float*)d_in[5];
  const float* b2 = (const float*)d_in[6];
  const float* w3 = (const float*)d_in[7];
  const float* b3 = (const float*)d_in[8];

  char* ws = (char*)d_ws;
  unsigned char* w0b = (unsigned char*)(ws + 0);
  unsigned char* w1b = (unsigned char*)(ws + (16ull << 20));
  unsigned char* w2b = (unsigned char*)(ws + (32ull << 20));
  unsigned char* w3b = (unsigned char*)(ws + (48ull << 20));
  int*           R   = (int*)(ws + (48ull << 20) + 65536);
  unsigned char* h1  = (unsigned char*)(ws + (64ull << 20));    // 64 MiB
  unsigned char* h2  = (unsigned char*)(ws + (128ull << 20));   // 64 MiB (aliases plane0; dead by then)
  unsigned char* Xp  = (unsigned char*)(ws + (128ull << 20));   // 3 planes x 64 MiB
  unsigned int*  cnt = (unsigned int*)(ws + (320ull << 20));
  unsigned int*  wl  = (unsigned int*)(ws + (320ull << 20) + 64);  // 16 MiB worklist
  float* out = (float*)d_out;

  binarize_swz_k<<<16384, 256, 0, stream>>>(w0, w0b, 1);
  binarize_swz_k<<<16384, 256, 0, stream>>>(w1, w1b, 1);
  binarize_swz_k<<<16384, 256, 0, stream>>>(w2, w2b, 1);
  binarize_swz_k<<<4,     256, 0, stream>>>(w3, w3b, 0);
  rowsum_k<<<1024, 256, 0, stream>>>(w0b, R);

  if (ws_size >= (384ull << 20)) {
    digitize3_k<<<65536, 256, 0, stream>>>(x, Xp);
    zeroc_k<<<1, 64, 0, stream>>>(cnt);
    gemm0p3_k<<<8192, 256, 0, stream>>>(Xp, w0b, R, b0, (signed char*)h1, wl, cnt);
    fixup_k<<<2048, 256, 0, stream>>>(x, w0b, b0, wl, cnt, (signed char*)h1);
  } else {
    gemm0f_k<<<dim3(32, 128), 512, 0, stream>>>(x, w0b, R, b0, (signed char*)h1);
  }
  gemm_bin_k<<<4096, 256, 0, stream>>>(h1, w1b, b1, (signed char*)h2);
  gemm_bin_k<<<4096, 256, 0, stream>>>(h2, w2b, b2, (signed char*)h1);
  final_k<<<4096, 256, 0, stream>>>(h1, w3b, b3, out);
}